// Round 11
// baseline (213.968 us; speedup 1.0000x reference)
//
#include <hip/hip_runtime.h>
#include <cstdint>

namespace {

constexpr int kS   = 2048;
constexpr int kNH  = 16;
constexpr int kHD  = 64;
constexpr int kH   = 1024;
constexpr int kB   = 2;
constexpr int kWin = 32;
constexpr int kNBlk = kS / kWin;  // 64
// exp(score/sqrt(64)) == exp2(score * log2(e)/8); folded into Q at projection
constexpr float kQScale = 0.18033688011112042f;

typedef __attribute__((ext_vector_type(8))) short short8v;          // 8 x bf16
typedef __attribute__((ext_vector_type(4))) float f32x4;            // MFMA C/D
typedef __attribute__((ext_vector_type(4))) unsigned short u16x4;
typedef __attribute__((ext_vector_type(8))) unsigned short u16x8;
typedef __attribute__((ext_vector_type(2))) unsigned int u32x2;

static __device__ __forceinline__ unsigned short f2bf(float f) {
  unsigned int u = __float_as_uint(f);
  return (unsigned short)((u + 0x7fffu + ((u >> 16) & 1u)) >> 16);
}
static __device__ __forceinline__ float bf2f(unsigned short b) {
  return __uint_as_float((unsigned int)b << 16);
}
static __device__ __forceinline__ void async16(const void* g, void* l) {
  __builtin_amdgcn_global_load_lds((__attribute__((address_space(1))) void*)(g),
                                   (__attribute__((address_space(3))) void*)(l),
                                   16, 0, 0);
}

// ---------------------------------------------------------------------------
// fp32 -> bf16 for hs (4M) and the four 1M weights, one dispatch.
// ---------------------------------------------------------------------------
__global__ __launch_bounds__(256) void cvt_bf16(
    const float* __restrict__ hs, const float* __restrict__ Wq,
    const float* __restrict__ Wk, const float* __restrict__ Wv,
    const float* __restrict__ Wo, unsigned short* __restrict__ out)
{
  const size_t idx = ((size_t)blockIdx.x * 256 + threadIdx.x) * 8;
  const int seg = (int)(idx >> 20);
  const size_t off = idx & ((1u << 20) - 1);
  const float* src;
  if (seg < 4)       src = hs + idx;
  else if (seg == 4) src = Wq + off;
  else if (seg == 5) src = Wk + off;
  else if (seg == 6) src = Wv + off;
  else               src = Wo + off;
  const float4 f0 = *(const float4*)(src);
  const float4 f1 = *(const float4*)(src + 4);
  u16x8 pk;
  pk[0] = f2bf(f0.x); pk[1] = f2bf(f0.y); pk[2] = f2bf(f0.z); pk[3] = f2bf(f0.w);
  pk[4] = f2bf(f1.x); pk[5] = f2bf(f1.y); pk[6] = f2bf(f1.z); pk[7] = f2bf(f1.w);
  *(u16x8*)(out + idx) = pk;
}

// ---------------------------------------------------------------------------
// bf16 MFMA GEMM, block (MT*32) x 128, BK=64 (unchanged from r7).
// ---------------------------------------------------------------------------
template <int MT, int EPI>
__global__ __launch_bounds__(256) void gemm_mfma(
    const unsigned short* __restrict__ A, const unsigned short* __restrict__ W,
    const float* __restrict__ b0, const float* __restrict__ b1,
    const float* __restrict__ b2, float* __restrict__ Cf,
    unsigned short* __restrict__ Dq, unsigned short* __restrict__ Dk,
    unsigned short* __restrict__ Dv, int M, int N, int K)
{
  constexpr int BMr = MT * 32;
  __shared__ unsigned short As[BMr * 64];
  __shared__ unsigned short Ws[128 * 64];
  const int tid  = threadIdx.x;
  const int wave = tid >> 6, lane = tid & 63;
  const int q16  = lane & 15, quad = lane >> 4;
  const int wm   = wave & 1,  wn   = wave >> 1;
  const int bm = blockIdx.y * BMr, bn = blockIdx.x * 128;

  const int lrow8 = lane >> 3;
  const int lch   = lane & 7;
  const int gch   = lch ^ lrow8;

  const unsigned short* gA[MT];
  unsigned short* lA[MT];
#pragma unroll
  for (int g = 0; g < MT; ++g) {
    const int row0 = wave * MT * 8 + g * 8;
    gA[g] = A + (size_t)(bm + row0 + lrow8) * K + gch * 8;
    lA[g] = As + row0 * 64;
  }
  const unsigned short* gW[4];
  unsigned short* lW[4];
#pragma unroll
  for (int g = 0; g < 4; ++g) {
    const int row0 = wave * 32 + g * 8;
    gW[g] = W + (size_t)(bn + row0 + lrow8) * K + gch * 8;
    lW[g] = Ws + row0 * 64;
  }

  const unsigned short* fA = As + (wm * (MT * 16) + q16) * 64;
  const unsigned short* fB = Ws + (wn * 64 + q16) * 64;
  const int sl0 = ((quad)     ^ (q16 & 7)) * 8;
  const int sl1 = ((quad + 4) ^ (q16 & 7)) * 8;

  const f32x4 zero = {0.f, 0.f, 0.f, 0.f};
  f32x4 acc[MT][4];
#pragma unroll
  for (int i = 0; i < MT; ++i)
#pragma unroll
    for (int j = 0; j < 4; ++j) acc[i][j] = zero;

  for (int k0 = 0; k0 < K; k0 += 64) {
    __syncthreads();
#pragma unroll
    for (int g = 0; g < MT; ++g) { async16(gA[g], lA[g]); gA[g] += 64; }
#pragma unroll
    for (int g = 0; g < 4; ++g)  { async16(gW[g], lW[g]); gW[g] += 64; }
    __syncthreads();

    short8v a[MT], b[4];
#pragma unroll
    for (int t = 0; t < MT; ++t) a[t] = *(const short8v*)(fA + t * 16 * 64 + sl0);
#pragma unroll
    for (int t = 0; t < 4; ++t)  b[t] = *(const short8v*)(fB + t * 16 * 64 + sl0);
#pragma unroll
    for (int mt = 0; mt < MT; ++mt)
#pragma unroll
      for (int nt = 0; nt < 4; ++nt)
        acc[mt][nt] = __builtin_amdgcn_mfma_f32_16x16x32_bf16(a[mt], b[nt], acc[mt][nt], 0, 0, 0);
#pragma unroll
    for (int t = 0; t < MT; ++t) a[t] = *(const short8v*)(fA + t * 16 * 64 + sl1);
#pragma unroll
    for (int t = 0; t < 4; ++t)  b[t] = *(const short8v*)(fB + t * 16 * 64 + sl1);
#pragma unroll
    for (int mt = 0; mt < MT; ++mt)
#pragma unroll
      for (int nt = 0; nt < 4; ++nt)
        acc[mt][nt] = __builtin_amdgcn_mfma_f32_16x16x32_bf16(a[mt], b[nt], acc[mt][nt], 0, 0, 0);
  }

#pragma unroll
  for (int nt = 0; nt < 4; ++nt) {
    const int col = bn + wn * 64 + nt * 16 + q16;
#pragma unroll
    for (int mt = 0; mt < MT; ++mt) {
      const int row0 = bm + wm * (MT * 16) + mt * 16 + quad * 4;
      const f32x4 av = acc[mt][nt];
      if (EPI == 0) {
        const float bv = b0[col];
#pragma unroll
        for (int r = 0; r < 4; ++r)
          Cf[(size_t)(row0 + r) * N + col] = av[r] + bv;
      } else {
        const int mat = col >> 10, c = col & 1023;
        const int b = row0 >> 11, s0 = row0 & 2047;
        const int h = c >> 6, d = c & 63;
        const size_t bhslot = (size_t)(b * kNH + h);
        if (mat == 0) {
          const float bv = b0[c];
          unsigned short* base = Dq + ((bhslot * kS + s0) * kHD + d);
#pragma unroll
          for (int r = 0; r < 4; ++r) base[(size_t)r * kHD] = f2bf((av[r] + bv) * kQScale);
        } else if (mat == 1) {
          const float bv = b1[c];
          unsigned short* base = Dk + ((bhslot * kS + s0) * kHD + d);
#pragma unroll
          for (int r = 0; r < 4; ++r) base[(size_t)r * kHD] = f2bf(av[r] + bv);
        } else {
          const float bv = b2[c];
          u16x4 pk;
          pk[0] = f2bf(av[0] + bv); pk[1] = f2bf(av[1] + bv);
          pk[2] = f2bf(av[2] + bv); pk[3] = f2bf(av[3] + bv);
          *(u16x4*)(Dv + (bhslot * kHD + d) * kS + s0) = pk;
        }
      }
    }
  }
}

// ---------------------------------------------------------------------------
// vrest[bh][bi][d] = sum over masked (future) blocks: sum_{jb>bi} block-sum.
// ---------------------------------------------------------------------------
__global__ __launch_bounds__(256) void vprefix_kernel(
    const unsigned short* __restrict__ vt, float* __restrict__ vrest)
{
  __shared__ float bsum[64][64];
  __shared__ float ptot[4][64];
  const int bh = blockIdx.x;
  const int d = threadIdx.x & 63, part = threadIdx.x >> 6;
  const unsigned short* base = vt + ((size_t)bh * kHD + d) * kS;
#pragma unroll 4
  for (int j = 0; j < 16; ++j) {
    const int jb = part * 16 + j;
    const unsigned short* p = base + jb * kWin;
    float s = 0.f;
#pragma unroll
    for (int i = 0; i < 4; ++i) {
      const u16x8 v = *(const u16x8*)(p + i * 8);
#pragma unroll
      for (int e = 0; e < 8; ++e) s += bf2f(v[e]);
    }
    bsum[jb][d] = s;
  }
  __syncthreads();
  float t = 0.f;
#pragma unroll
  for (int j = 0; j < 16; ++j) t += bsum[part * 16 + j][d];
  ptot[part][d] = t;
  __syncthreads();
  float s = 0.f;
  for (int p2 = part + 1; p2 < 4; ++p2) s += ptot[p2][d];
#pragma unroll
  for (int j = 15; j >= 0; --j) {
    const int bi = part * 16 + j;
    vrest[((size_t)bh * kNBlk + bi) * kHD + d] = s;
    s += bsum[bi][d];
  }
}

// ---------------------------------------------------------------------------
// MFMA attention (r10 kernel body, untouched). r11 change: pr comes from a
// WORK-BALANCING permutation of blockIdx instead of the monotone map.
// MI355X assigns block b -> XCD b%8; a CU's co-resident blocks are index-
// neighbors at stride 8/32, so monotone pr gave each CU 4 equal-work blocks
// -> 8x work spread across CUs -> 26% time-avg occupancy (r10 measured).
// With j=(b>>3)&3, k=b>>5:  pr = k / 31-k / (k+16)&31 / (15-k)&31 — any
// four stride-8 neighbors sum to 62 (constant), each (bh,pr) occurs once.
// ---------------------------------------------------------------------------
template <int QT0>
__device__ __forceinline__ void attn_iter(
    const unsigned short* __restrict__ Kb, const unsigned short* __restrict__ Vtb,
    int jb, const short8v qf[4][2], unsigned short* __restrict__ esw,
    int q16, int quad, int swz, f32x4 acc[4][4], float dAcc[4])
{
  const unsigned short* Kj = Kb + (size_t)jb * kWin * kHD;
  short8v kf[2][2];
#pragma unroll
  for (int kt = 0; kt < 2; ++kt)
#pragma unroll
    for (int ks = 0; ks < 2; ++ks)
      kf[kt][ks] = *(const short8v*)(Kj + (kt * 16 + q16) * kHD + ks * 32 + quad * 8);

  const f32x4 zero = {0.f, 0.f, 0.f, 0.f};
#pragma unroll
  for (int kt = 0; kt < 2; ++kt) {
    f32x4 st[4];
#pragma unroll
    for (int qt = QT0; qt < 4; ++qt) {
      f32x4 c = zero;
      c = __builtin_amdgcn_mfma_f32_16x16x32_bf16(kf[kt][0], qf[qt][0], c, 0, 0, 0);
      c = __builtin_amdgcn_mfma_f32_16x16x32_bf16(kf[kt][1], qf[qt][1], c, 0, 0, 0);
      st[qt] = c;
    }
    const int g = kt * 2 + (quad >> 1);
    const int col = ((g ^ swz) * 8) + (quad & 1) * 4;
#pragma unroll
    for (int qt = QT0; qt < 4; ++qt) {
      const float e0 = __builtin_amdgcn_exp2f(st[qt][0]);
      const float e1 = __builtin_amdgcn_exp2f(st[qt][1]);
      const float e2 = __builtin_amdgcn_exp2f(st[qt][2]);
      const float e3 = __builtin_amdgcn_exp2f(st[qt][3]);
      dAcc[qt] += (e0 + e1) + (e2 + e3);
      const unsigned int r0 = __float_as_uint(e0) + 0x8000u;
      const unsigned int r1 = __float_as_uint(e1) + 0x8000u;
      const unsigned int r2 = __float_as_uint(e2) + 0x8000u;
      const unsigned int r3 = __float_as_uint(e3) + 0x8000u;
      u32x2 w;
      w[0] = __builtin_amdgcn_perm(r1, r0, 0x07060302u);
      w[1] = __builtin_amdgcn_perm(r3, r2, 0x07060302u);
      *(u32x2*)(esw + (qt * 16 + q16) * 32 + col) = w;
    }
  }
  short8v af[4];
#pragma unroll
  for (int mt = QT0; mt < 4; ++mt)
    af[mt] = *(const short8v*)(esw + (mt * 16 + q16) * 32 + (quad ^ swz) * 8);
#pragma unroll
  for (int nt = 0; nt < 4; ++nt) {
    const short8v vfv = *(const short8v*)(Vtb + (size_t)(nt * 16 + q16) * kS +
                                          jb * kWin + quad * 8);
#pragma unroll
    for (int mt = QT0; mt < 4; ++mt)
      acc[mt][nt] = __builtin_amdgcn_mfma_f32_16x16x32_bf16(af[mt], vfv, acc[mt][nt], 0, 0, 0);
  }
}

__global__ __launch_bounds__(256, 3) void attn_mfma(
    const unsigned short* __restrict__ qb, const unsigned short* __restrict__ kb,
    const unsigned short* __restrict__ vtb, const float* __restrict__ vrest,
    unsigned short* __restrict__ ctx)
{
  __shared__ union SM {
    unsigned short es[4][2048];   // per-wave E tiles during the loop (16 KB)
    float part[4096];             // merge buffer after the loop (16 KB alias)
  } sm;
  __shared__ float den[4][64];    // 1 KB; total LDS 17.4 KB

  const int tid  = threadIdx.x;
  const int wave = tid >> 6;
  const int lane = tid & 63;
  const int q16  = lane & 15;
  const int quad = lane >> 4;
  const int bidx = blockIdx.x;
  const int bh = bidx & 31;                    // bh fastest -> XCD locality
  // work-balancing pr permutation (see header comment)
  const int jsel = (bidx >> 3) & 3;
  const int kidx = bidx >> 5;
  const int kk = (jsel & 2) ? ((kidx + 16) & 31) : kidx;
  const int pr = (jsel & 1) ? ((31 - kk) & 31) : kk;
  const int bilo = pr * 2, bihi = pr * 2 + 1;
  const int b  = bh >> 4, h = bh & 15;

  const unsigned short* Qb  = qb  + ((size_t)bh * kS + (size_t)pr * 64) * kHD;
  const unsigned short* Kb  = kb  + (size_t)bh * kS * kHD;
  const unsigned short* Vtb = vtb + (size_t)bh * kHD * kS;

  short8v qf[4][2];
#pragma unroll
  for (int qt = 0; qt < 4; ++qt)
#pragma unroll
    for (int ks = 0; ks < 2; ++ks)
      qf[qt][ks] = *(const short8v*)(Qb + (qt * 16 + q16) * kHD + ks * 32 + quad * 8);

  const f32x4 zero = {0.f, 0.f, 0.f, 0.f};
  f32x4 acc[4][4];
#pragma unroll
  for (int mt = 0; mt < 4; ++mt)
#pragma unroll
    for (int nt = 0; nt < 4; ++nt) acc[mt][nt] = zero;
  float dAcc[4] = {0.f, 0.f, 0.f, 0.f};

  unsigned short* esw = sm.es[wave];
  const int swz = (q16 >> 2) & 3;

  for (int jb = wave; jb <= bilo; jb += 4)
    attn_iter<0>(Kb, Vtb, jb, qf, esw, q16, quad, swz, acc, dAcc);
  if ((bihi & 3) == wave)   // the one extra block seen only by the upper qblock
    attn_iter<2>(Kb, Vtb, bihi, qf, esw, q16, quad, swz, acc, dAcc);

  // full denom per (qt, q16): reduce over quads (keys)
#pragma unroll
  for (int qt = 0; qt < 4; ++qt) {
    dAcc[qt] += __shfl_xor(dAcc[qt], 16);
    dAcc[qt] += __shfl_xor(dAcc[qt], 32);
  }

  __syncthreads();  // es use done before aliasing as part
  if (quad == 0) {
#pragma unroll
    for (int qt = 0; qt < 4; ++qt) den[wave][qt * 16 + q16] = dAcc[qt];
  }
  // sequential merge through the single 16 KB buffer (bank-free: idx*64+lane)
  if (wave == 0) {
#pragma unroll
    for (int mt = 0; mt < 4; ++mt)
#pragma unroll
      for (int nt = 0; nt < 4; ++nt)
#pragma unroll
        for (int r = 0; r < 4; ++r)
          sm.part[((mt * 4 + nt) * 4 + r) * 64 + lane] = acc[mt][nt][r];
  }
  __syncthreads();
  if (wave == 1) {
#pragma unroll
    for (int mt = 0; mt < 4; ++mt)
#pragma unroll
      for (int nt = 0; nt < 4; ++nt)
#pragma unroll
        for (int r = 0; r < 4; ++r)
          sm.part[((mt * 4 + nt) * 4 + r) * 64 + lane] += acc[mt][nt][r];
  }
  __syncthreads();
  if (wave == 2) {
#pragma unroll
    for (int mt = 0; mt < 4; ++mt)
#pragma unroll
      for (int nt = 0; nt < 4; ++nt)
#pragma unroll
        for (int r = 0; r < 4; ++r)
          sm.part[((mt * 4 + nt) * 4 + r) * 64 + lane] += acc[mt][nt][r];
  }
  __syncthreads();
  if (wave == 3) {
#pragma unroll
    for (int mt = 0; mt < 4; ++mt)
#pragma unroll
      for (int nt = 0; nt < 4; ++nt)
#pragma unroll
        for (int r = 0; r < 4; ++r)
          sm.part[((mt * 4 + nt) * 4 + r) * 64 + lane] += acc[mt][nt][r];
  }
  __syncthreads();

  // finalize: wave w owns dim-tile nt==w; rows 0..31 -> bilo, 32..63 -> bihi
  {
    const int nt = wave;
    const int dim = nt * 16 + q16;
    const float vrlo = vrest[((size_t)bh * kNBlk + bilo) * kHD + dim];
    const float vrhi = vrest[((size_t)bh * kNBlk + bihi) * kHD + dim];
    const float nrlo = 32.0f * (float)((kNBlk - 1) - bilo);
    const float nrhi = 32.0f * (float)((kNBlk - 1) - bihi);
    unsigned short* outb = ctx + ((size_t)b * kS + (size_t)pr * 64) * kH + h * kHD;
#pragma unroll
    for (int mt = 0; mt < 4; ++mt) {
      const float vr = (mt < 2) ? vrlo : vrhi;
      const float nr = (mt < 2) ? nrlo : nrhi;
#pragma unroll
      for (int r = 0; r < 4; ++r) {
        const int idx = ((mt * 4 + nt) * 4 + r) * 64 + lane;
        const int qrow = mt * 16 + quad * 4 + r;
        const float dsum = den[0][qrow] + den[1][qrow] +
                           den[2][qrow] + den[3][qrow] + nr;
        outb[(size_t)qrow * kH + dim] = f2bf((sm.part[idx] + vr) / dsum);
      }
    }
  }
}

}  // namespace

extern "C" void kernel_launch(void* const* d_in, const int* in_sizes, int n_in,
                              void* d_out, int out_size, void* d_ws, size_t ws_size,
                              hipStream_t stream) {
  const float* hs = (const float*)d_in[0];
  const float* Wq = (const float*)d_in[1];
  const float* bq = (const float*)d_in[2];
  const float* Wk = (const float*)d_in[3];
  const float* bk = (const float*)d_in[4];
  const float* Wv = (const float*)d_in[5];
  const float* bv = (const float*)d_in[6];
  const float* Wo = (const float*)d_in[7];
  const float* bo = (const float*)d_in[8];

  char* wsb = (char*)d_ws;
  unsigned short* hsb   = (unsigned short*)(wsb);                 //  8 MB [M][K] bf16
  unsigned short* wqkv  = hsb + (4u << 20);                       //  6 MB [3072][1024]
  unsigned short* wob   = hsb + (7u << 20);                       //  2 MB
  unsigned short* qbuf  = (unsigned short*)(wsb + (16u << 20));   //  8 MB [bh][s][d]
  unsigned short* kbuf  = (unsigned short*)(wsb + (24u << 20));   //  8 MB [bh][s][d]
  unsigned short* vtbuf = (unsigned short*)(wsb + (32u << 20));   //  8 MB [bh][d][s]
  unsigned short* ctxb  = (unsigned short*)(wsb + (40u << 20));   //  8 MB [M][H] bf16
  float*          vrest = (float*)         (wsb + (48u << 20));   // 512 KB [bh][bi][d]

  const int M = kB * kS;  // 4096

  cvt_bf16<<<4096, 256, 0, stream>>>(hs, Wq, Wk, Wv, Wo, hsb);
  gemm_mfma<4, 1><<<dim3(3072 / 128, M / 128), 256, 0, stream>>>(
      hsb, wqkv, bq, bk, bv, nullptr, qbuf, kbuf, vtbuf, M, 3072, kH);
  vprefix_kernel<<<kB * kNH, 256, 0, stream>>>(vtbuf, vrest);
  attn_mfma<<<(kNBlk / 2) * kB * kNH, 256, 0, stream>>>(qbuf, kbuf, vtbuf, vrest, ctxb);
  gemm_mfma<2, 0><<<dim3(kH / 128, M / 64), 256, 0, stream>>>(
      ctxb, wob, bo, nullptr, nullptr, (float*)d_out, nullptr, nullptr, nullptr,
      M, kH, kH);
}

// Round 12
// 194.726 us; speedup vs baseline: 1.0988x; 1.0988x over previous
//
#include <hip/hip_runtime.h>
#include <cstdint>

namespace {

constexpr int kS   = 2048;
constexpr int kNH  = 16;
constexpr int kHD  = 64;
constexpr int kH   = 1024;
constexpr int kB   = 2;
constexpr int kWin = 32;
constexpr int kNBlk = kS / kWin;  // 64
// exp(score/sqrt(64)) == exp2(score * log2(e)/8); folded into Q at projection
constexpr float kQScale = 0.18033688011112042f;

typedef __attribute__((ext_vector_type(8))) short short8v;          // 8 x bf16
typedef __attribute__((ext_vector_type(4))) float f32x4;            // MFMA C/D
typedef __attribute__((ext_vector_type(4))) unsigned short u16x4;
typedef __attribute__((ext_vector_type(8))) unsigned short u16x8;
typedef __attribute__((ext_vector_type(2))) unsigned int u32x2;

static __device__ __forceinline__ unsigned short f2bf(float f) {
  unsigned int u = __float_as_uint(f);
  return (unsigned short)((u + 0x7fffu + ((u >> 16) & 1u)) >> 16);
}
static __device__ __forceinline__ float bf2f(unsigned short b) {
  return __uint_as_float((unsigned int)b << 16);
}
static __device__ __forceinline__ void async16(const void* g, void* l) {
  __builtin_amdgcn_global_load_lds((__attribute__((address_space(1))) void*)(g),
                                   (__attribute__((address_space(3))) void*)(l),
                                   16, 0, 0);
}

// ---------------------------------------------------------------------------
// fp32 -> bf16 for hs (4M) and the four 1M weights, one dispatch.
// ---------------------------------------------------------------------------
__global__ __launch_bounds__(256) void cvt_bf16(
    const float* __restrict__ hs, const float* __restrict__ Wq,
    const float* __restrict__ Wk, const float* __restrict__ Wv,
    const float* __restrict__ Wo, unsigned short* __restrict__ out)
{
  const size_t idx = ((size_t)blockIdx.x * 256 + threadIdx.x) * 8;
  const int seg = (int)(idx >> 20);
  const size_t off = idx & ((1u << 20) - 1);
  const float* src;
  if (seg < 4)       src = hs + idx;
  else if (seg == 4) src = Wq + off;
  else if (seg == 5) src = Wk + off;
  else if (seg == 6) src = Wv + off;
  else               src = Wo + off;
  const float4 f0 = *(const float4*)(src);
  const float4 f1 = *(const float4*)(src + 4);
  u16x8 pk;
  pk[0] = f2bf(f0.x); pk[1] = f2bf(f0.y); pk[2] = f2bf(f0.z); pk[3] = f2bf(f0.w);
  pk[4] = f2bf(f1.x); pk[5] = f2bf(f1.y); pk[6] = f2bf(f1.z); pk[7] = f2bf(f1.w);
  *(u16x8*)(out + idx) = pk;
}

// ---------------------------------------------------------------------------
// bf16 MFMA GEMM, block (MT*32) x 128, BK=64 (unchanged from r7).
// ---------------------------------------------------------------------------
template <int MT, int EPI>
__global__ __launch_bounds__(256) void gemm_mfma(
    const unsigned short* __restrict__ A, const unsigned short* __restrict__ W,
    const float* __restrict__ b0, const float* __restrict__ b1,
    const float* __restrict__ b2, float* __restrict__ Cf,
    unsigned short* __restrict__ Dq, unsigned short* __restrict__ Dk,
    unsigned short* __restrict__ Dv, int M, int N, int K)
{
  constexpr int BMr = MT * 32;
  __shared__ unsigned short As[BMr * 64];
  __shared__ unsigned short Ws[128 * 64];
  const int tid  = threadIdx.x;
  const int wave = tid >> 6, lane = tid & 63;
  const int q16  = lane & 15, quad = lane >> 4;
  const int wm   = wave & 1,  wn   = wave >> 1;
  const int bm = blockIdx.y * BMr, bn = blockIdx.x * 128;

  const int lrow8 = lane >> 3;
  const int lch   = lane & 7;
  const int gch   = lch ^ lrow8;

  const unsigned short* gA[MT];
  unsigned short* lA[MT];
#pragma unroll
  for (int g = 0; g < MT; ++g) {
    const int row0 = wave * MT * 8 + g * 8;
    gA[g] = A + (size_t)(bm + row0 + lrow8) * K + gch * 8;
    lA[g] = As + row0 * 64;
  }
  const unsigned short* gW[4];
  unsigned short* lW[4];
#pragma unroll
  for (int g = 0; g < 4; ++g) {
    const int row0 = wave * 32 + g * 8;
    gW[g] = W + (size_t)(bn + row0 + lrow8) * K + gch * 8;
    lW[g] = Ws + row0 * 64;
  }

  const unsigned short* fA = As + (wm * (MT * 16) + q16) * 64;
  const unsigned short* fB = Ws + (wn * 64 + q16) * 64;
  const int sl0 = ((quad)     ^ (q16 & 7)) * 8;
  const int sl1 = ((quad + 4) ^ (q16 & 7)) * 8;

  const f32x4 zero = {0.f, 0.f, 0.f, 0.f};
  f32x4 acc[MT][4];
#pragma unroll
  for (int i = 0; i < MT; ++i)
#pragma unroll
    for (int j = 0; j < 4; ++j) acc[i][j] = zero;

  for (int k0 = 0; k0 < K; k0 += 64) {
    __syncthreads();
#pragma unroll
    for (int g = 0; g < MT; ++g) { async16(gA[g], lA[g]); gA[g] += 64; }
#pragma unroll
    for (int g = 0; g < 4; ++g)  { async16(gW[g], lW[g]); gW[g] += 64; }
    __syncthreads();

    short8v a[MT], b[4];
#pragma unroll
    for (int t = 0; t < MT; ++t) a[t] = *(const short8v*)(fA + t * 16 * 64 + sl0);
#pragma unroll
    for (int t = 0; t < 4; ++t)  b[t] = *(const short8v*)(fB + t * 16 * 64 + sl0);
#pragma unroll
    for (int mt = 0; mt < MT; ++mt)
#pragma unroll
      for (int nt = 0; nt < 4; ++nt)
        acc[mt][nt] = __builtin_amdgcn_mfma_f32_16x16x32_bf16(a[mt], b[nt], acc[mt][nt], 0, 0, 0);
#pragma unroll
    for (int t = 0; t < MT; ++t) a[t] = *(const short8v*)(fA + t * 16 * 64 + sl1);
#pragma unroll
    for (int t = 0; t < 4; ++t)  b[t] = *(const short8v*)(fB + t * 16 * 64 + sl1);
#pragma unroll
    for (int mt = 0; mt < MT; ++mt)
#pragma unroll
      for (int nt = 0; nt < 4; ++nt)
        acc[mt][nt] = __builtin_amdgcn_mfma_f32_16x16x32_bf16(a[mt], b[nt], acc[mt][nt], 0, 0, 0);
  }

#pragma unroll
  for (int nt = 0; nt < 4; ++nt) {
    const int col = bn + wn * 64 + nt * 16 + q16;
#pragma unroll
    for (int mt = 0; mt < MT; ++mt) {
      const int row0 = bm + wm * (MT * 16) + mt * 16 + quad * 4;
      const f32x4 av = acc[mt][nt];
      if (EPI == 0) {
        const float bv = b0[col];
#pragma unroll
        for (int r = 0; r < 4; ++r)
          Cf[(size_t)(row0 + r) * N + col] = av[r] + bv;
      } else {
        const int mat = col >> 10, c = col & 1023;
        const int b = row0 >> 11, s0 = row0 & 2047;
        const int h = c >> 6, d = c & 63;
        const size_t bhslot = (size_t)(b * kNH + h);
        if (mat == 0) {
          const float bv = b0[c];
          unsigned short* base = Dq + ((bhslot * kS + s0) * kHD + d);
#pragma unroll
          for (int r = 0; r < 4; ++r) base[(size_t)r * kHD] = f2bf((av[r] + bv) * kQScale);
        } else if (mat == 1) {
          const float bv = b1[c];
          unsigned short* base = Dk + ((bhslot * kS + s0) * kHD + d);
#pragma unroll
          for (int r = 0; r < 4; ++r) base[(size_t)r * kHD] = f2bf(av[r] + bv);
        } else {
          const float bv = b2[c];
          u16x4 pk;
          pk[0] = f2bf(av[0] + bv); pk[1] = f2bf(av[1] + bv);
          pk[2] = f2bf(av[2] + bv); pk[3] = f2bf(av[3] + bv);
          *(u16x4*)(Dv + (bhslot * kHD + d) * kS + s0) = pk;
        }
      }
    }
  }
}

// ---------------------------------------------------------------------------
// vrest[bh][bi][d] = sum over masked (future) blocks: sum_{jb>bi} block-sum.
// ---------------------------------------------------------------------------
__global__ __launch_bounds__(256) void vprefix_kernel(
    const unsigned short* __restrict__ vt, float* __restrict__ vrest)
{
  __shared__ float bsum[64][64];
  __shared__ float ptot[4][64];
  const int bh = blockIdx.x;
  const int d = threadIdx.x & 63, part = threadIdx.x >> 6;
  const unsigned short* base = vt + ((size_t)bh * kHD + d) * kS;
#pragma unroll 4
  for (int j = 0; j < 16; ++j) {
    const int jb = part * 16 + j;
    const unsigned short* p = base + jb * kWin;
    float s = 0.f;
#pragma unroll
    for (int i = 0; i < 4; ++i) {
      const u16x8 v = *(const u16x8*)(p + i * 8);
#pragma unroll
      for (int e = 0; e < 8; ++e) s += bf2f(v[e]);
    }
    bsum[jb][d] = s;
  }
  __syncthreads();
  float t = 0.f;
#pragma unroll
  for (int j = 0; j < 16; ++j) t += bsum[part * 16 + j][d];
  ptot[part][d] = t;
  __syncthreads();
  float s = 0.f;
  for (int p2 = part + 1; p2 < 4; ++p2) s += ptot[p2][d];
#pragma unroll
  for (int j = 15; j >= 0; --j) {
    const int bi = part * 16 + j;
    vrest[((size_t)bh * kNBlk + bi) * kHD + d] = s;
    s += bsum[bi][d];
  }
}

// ---------------------------------------------------------------------------
// MFMA attention, QB=2. r12: (a) pr map reverted to monotone heavy-first
// (r11 permutation regressed — LPT-like order wins under partial residency);
// (b) vf loads moved to AFTER exp/pack, BEFORE the af ds_reads: all 4 in
// flight together, latency overlaps the es LDS round-trip, live range ~10
// instructions (r7 placement = 4 serial L2 waits; r8 start-of-iter = spill).
// ---------------------------------------------------------------------------
template <int QT0>
__device__ __forceinline__ void attn_iter(
    const unsigned short* __restrict__ Kb, const unsigned short* __restrict__ Vtb,
    int jb, const short8v qf[4][2], unsigned short* __restrict__ esw,
    int q16, int quad, int swz, f32x4 acc[4][4], float dAcc[4])
{
  const unsigned short* Kj = Kb + (size_t)jb * kWin * kHD;
  short8v kf[2][2];
#pragma unroll
  for (int kt = 0; kt < 2; ++kt)
#pragma unroll
    for (int ks = 0; ks < 2; ++ks)
      kf[kt][ks] = *(const short8v*)(Kj + (kt * 16 + q16) * kHD + ks * 32 + quad * 8);

  const f32x4 zero = {0.f, 0.f, 0.f, 0.f};
#pragma unroll
  for (int kt = 0; kt < 2; ++kt) {
    f32x4 st[4];
#pragma unroll
    for (int qt = QT0; qt < 4; ++qt) {
      f32x4 c = zero;
      c = __builtin_amdgcn_mfma_f32_16x16x32_bf16(kf[kt][0], qf[qt][0], c, 0, 0, 0);
      c = __builtin_amdgcn_mfma_f32_16x16x32_bf16(kf[kt][1], qf[qt][1], c, 0, 0, 0);
      st[qt] = c;
    }
    const int g = kt * 2 + (quad >> 1);
    const int col = ((g ^ swz) * 8) + (quad & 1) * 4;
#pragma unroll
    for (int qt = QT0; qt < 4; ++qt) {
      const float e0 = __builtin_amdgcn_exp2f(st[qt][0]);
      const float e1 = __builtin_amdgcn_exp2f(st[qt][1]);
      const float e2 = __builtin_amdgcn_exp2f(st[qt][2]);
      const float e3 = __builtin_amdgcn_exp2f(st[qt][3]);
      dAcc[qt] += (e0 + e1) + (e2 + e3);
      const unsigned int r0 = __float_as_uint(e0) + 0x8000u;
      const unsigned int r1 = __float_as_uint(e1) + 0x8000u;
      const unsigned int r2 = __float_as_uint(e2) + 0x8000u;
      const unsigned int r3 = __float_as_uint(e3) + 0x8000u;
      u32x2 w;
      w[0] = __builtin_amdgcn_perm(r1, r0, 0x07060302u);
      w[1] = __builtin_amdgcn_perm(r3, r2, 0x07060302u);
      *(u32x2*)(esw + (qt * 16 + q16) * 32 + col) = w;
    }
  }
  // vf loads HERE: 4 independent b128 loads in flight while the es LDS
  // round-trip (lgkm) drains; short live range -> no spill.
  short8v vf[4];
#pragma unroll
  for (int nt = 0; nt < 4; ++nt)
    vf[nt] = *(const short8v*)(Vtb + (size_t)(nt * 16 + q16) * kS +
                               jb * kWin + quad * 8);
  short8v af[4];
#pragma unroll
  for (int mt = QT0; mt < 4; ++mt)
    af[mt] = *(const short8v*)(esw + (mt * 16 + q16) * 32 + (quad ^ swz) * 8);
#pragma unroll
  for (int nt = 0; nt < 4; ++nt) {
#pragma unroll
    for (int mt = QT0; mt < 4; ++mt)
      acc[mt][nt] = __builtin_amdgcn_mfma_f32_16x16x32_bf16(af[mt], vf[nt], acc[mt][nt], 0, 0, 0);
  }
}

__global__ __launch_bounds__(256, 3) void attn_mfma(
    const unsigned short* __restrict__ qb, const unsigned short* __restrict__ kb,
    const unsigned short* __restrict__ vtb, const float* __restrict__ vrest,
    unsigned short* __restrict__ ctx)
{
  __shared__ union SM {
    unsigned short es[4][2048];   // per-wave E tiles during the loop (16 KB)
    float part[4096];             // merge buffer after the loop (16 KB alias)
  } sm;
  __shared__ float den[4][64];    // 1 KB; total LDS 17.4 KB

  const int tid  = threadIdx.x;
  const int wave = tid >> 6;
  const int lane = tid & 63;
  const int q16  = lane & 15;
  const int quad = lane >> 4;
  const int bh = blockIdx.x & 31;              // bh fastest -> XCD locality
  const int pr = 31 - (blockIdx.x >> 5);       // heavy pairs first (LPT)
  const int bilo = pr * 2, bihi = pr * 2 + 1;
  const int b  = bh >> 4, h = bh & 15;

  const unsigned short* Qb  = qb  + ((size_t)bh * kS + (size_t)pr * 64) * kHD;
  const unsigned short* Kb  = kb  + (size_t)bh * kS * kHD;
  const unsigned short* Vtb = vtb + (size_t)bh * kHD * kS;

  short8v qf[4][2];
#pragma unroll
  for (int qt = 0; qt < 4; ++qt)
#pragma unroll
    for (int ks = 0; ks < 2; ++ks)
      qf[qt][ks] = *(const short8v*)(Qb + (qt * 16 + q16) * kHD + ks * 32 + quad * 8);

  const f32x4 zero = {0.f, 0.f, 0.f, 0.f};
  f32x4 acc[4][4];
#pragma unroll
  for (int mt = 0; mt < 4; ++mt)
#pragma unroll
    for (int nt = 0; nt < 4; ++nt) acc[mt][nt] = zero;
  float dAcc[4] = {0.f, 0.f, 0.f, 0.f};

  unsigned short* esw = sm.es[wave];
  const int swz = (q16 >> 2) & 3;

  for (int jb = wave; jb <= bilo; jb += 4)
    attn_iter<0>(Kb, Vtb, jb, qf, esw, q16, quad, swz, acc, dAcc);
  if ((bihi & 3) == wave)   // the one extra block seen only by the upper qblock
    attn_iter<2>(Kb, Vtb, bihi, qf, esw, q16, quad, swz, acc, dAcc);

  // full denom per (qt, q16): reduce over quads (keys)
#pragma unroll
  for (int qt = 0; qt < 4; ++qt) {
    dAcc[qt] += __shfl_xor(dAcc[qt], 16);
    dAcc[qt] += __shfl_xor(dAcc[qt], 32);
  }

  __syncthreads();  // es use done before aliasing as part
  if (quad == 0) {
#pragma unroll
    for (int qt = 0; qt < 4; ++qt) den[wave][qt * 16 + q16] = dAcc[qt];
  }
  // sequential merge through the single 16 KB buffer (bank-free: idx*64+lane)
  if (wave == 0) {
#pragma unroll
    for (int mt = 0; mt < 4; ++mt)
#pragma unroll
      for (int nt = 0; nt < 4; ++nt)
#pragma unroll
        for (int r = 0; r < 4; ++r)
          sm.part[((mt * 4 + nt) * 4 + r) * 64 + lane] = acc[mt][nt][r];
  }
  __syncthreads();
  if (wave == 1) {
#pragma unroll
    for (int mt = 0; mt < 4; ++mt)
#pragma unroll
      for (int nt = 0; nt < 4; ++nt)
#pragma unroll
        for (int r = 0; r < 4; ++r)
          sm.part[((mt * 4 + nt) * 4 + r) * 64 + lane] += acc[mt][nt][r];
  }
  __syncthreads();
  if (wave == 2) {
#pragma unroll
    for (int mt = 0; mt < 4; ++mt)
#pragma unroll
      for (int nt = 0; nt < 4; ++nt)
#pragma unroll
        for (int r = 0; r < 4; ++r)
          sm.part[((mt * 4 + nt) * 4 + r) * 64 + lane] += acc[mt][nt][r];
  }
  __syncthreads();
  if (wave == 3) {
#pragma unroll
    for (int mt = 0; mt < 4; ++mt)
#pragma unroll
      for (int nt = 0; nt < 4; ++nt)
#pragma unroll
        for (int r = 0; r < 4; ++r)
          sm.part[((mt * 4 + nt) * 4 + r) * 64 + lane] += acc[mt][nt][r];
  }
  __syncthreads();

  // finalize: wave w owns dim-tile nt==w; rows 0..31 -> bilo, 32..63 -> bihi
  {
    const int nt = wave;
    const int dim = nt * 16 + q16;
    const float vrlo = vrest[((size_t)bh * kNBlk + bilo) * kHD + dim];
    const float vrhi = vrest[((size_t)bh * kNBlk + bihi) * kHD + dim];
    const float nrlo = 32.0f * (float)((kNBlk - 1) - bilo);
    const float nrhi = 32.0f * (float)((kNBlk - 1) - bihi);
    unsigned short* outb = ctx + ((size_t)b * kS + (size_t)pr * 64) * kH + h * kHD;
#pragma unroll
    for (int mt = 0; mt < 4; ++mt) {
      const float vr = (mt < 2) ? vrlo : vrhi;
      const float nr = (mt < 2) ? nrlo : nrhi;
#pragma unroll
      for (int r = 0; r < 4; ++r) {
        const int idx = ((mt * 4 + nt) * 4 + r) * 64 + lane;
        const int qrow = mt * 16 + quad * 4 + r;
        const float dsum = den[0][qrow] + den[1][qrow] +
                           den[2][qrow] + den[3][qrow] + nr;
        outb[(size_t)qrow * kH + dim] = f2bf((sm.part[idx] + vr) / dsum);
      }
    }
  }
}

}  // namespace

extern "C" void kernel_launch(void* const* d_in, const int* in_sizes, int n_in,
                              void* d_out, int out_size, void* d_ws, size_t ws_size,
                              hipStream_t stream) {
  const float* hs = (const float*)d_in[0];
  const float* Wq = (const float*)d_in[1];
  const float* bq = (const float*)d_in[2];
  const float* Wk = (const float*)d_in[3];
  const float* bk = (const float*)d_in[4];
  const float* Wv = (const float*)d_in[5];
  const float* bv = (const float*)d_in[6];
  const float* Wo = (const float*)d_in[7];
  const float* bo = (const float*)d_in[8];

  char* wsb = (char*)d_ws;
  unsigned short* hsb   = (unsigned short*)(wsb);                 //  8 MB [M][K] bf16
  unsigned short* wqkv  = hsb + (4u << 20);                       //  6 MB [3072][1024]
  unsigned short* wob   = hsb + (7u << 20);                       //  2 MB
  unsigned short* qbuf  = (unsigned short*)(wsb + (16u << 20));   //  8 MB [bh][s][d]
  unsigned short* kbuf  = (unsigned short*)(wsb + (24u << 20));   //  8 MB [bh][s][d]
  unsigned short* vtbuf = (unsigned short*)(wsb + (32u << 20));   //  8 MB [bh][d][s]
  unsigned short* ctxb  = (unsigned short*)(wsb + (40u << 20));   //  8 MB [M][H] bf16
  float*          vrest = (float*)         (wsb + (48u << 20));   // 512 KB [bh][bi][d]

  const int M = kB * kS;  // 4096

  cvt_bf16<<<4096, 256, 0, stream>>>(hs, Wq, Wk, Wv, Wo, hsb);
  gemm_mfma<4, 1><<<dim3(3072 / 128, M / 128), 256, 0, stream>>>(
      hsb, wqkv, bq, bk, bv, nullptr, qbuf, kbuf, vtbuf, M, 3072, kH);
  vprefix_kernel<<<kB * kNH, 256, 0, stream>>>(vtbuf, vrest);
  attn_mfma<<<(kNBlk / 2) * kB * kNH, 256, 0, stream>>>(qbuf, kbuf, vtbuf, vrest, ctxb);
  gemm_mfma<2, 0><<<dim3(kH / 128, M / 64), 256, 0, stream>>>(
      ctxb, wob, bo, nullptr, nullptr, (float*)d_out, nullptr, nullptr, nullptr,
      M, kH, kH);
}